// Round 1
// baseline (4400.186 us; speedup 1.0000x reference)
//
#include <hip/hip_runtime.h>

// ---------------- constants ----------------
#define T_ENC 64
#define T_DEC 99

// bf16 weight workspace layout (elements)
#define O_EWHH0 0
#define O_EWIH  49152
#define O_EWHH  196608
#define O_DWHH0 344064
#define O_DWIH  393216
#define O_DWHH  540672
#define O_LIN1  688128
#define W_TOTAL 704512

// output layout (f32 elements)
#define DEC_OUT_OFF 0
#define DEC_HID_OFF 1638400
#define ENC_OUT_OFF 3735552
#define ENC_HID_OFF 37289984
#define LOSS_OFF    39387136

typedef short short8_t __attribute__((ext_vector_type(8)));
typedef float f32x4 __attribute__((ext_vector_type(4)));

#define MFMA16(a, b, c) __builtin_amdgcn_mfma_f32_16x16x32_bf16((a), (b), (c), 0, 0, 0)

__device__ __forceinline__ unsigned short f2bf(float f) {
  unsigned u = __builtin_bit_cast(unsigned, f);
  u = (u + 0x7FFFu + ((u >> 16) & 1u)) >> 16;
  return (unsigned short)u;
}
__device__ __forceinline__ float sigm(float x) { return 1.f / (1.f + __expf(-x)); }
__device__ __forceinline__ float tanh_fast(float x) {
  x = fminf(fmaxf(x, -30.f), 30.f);
  float e = __expf(-2.f * x);
  return (1.f - e) / (1.f + e);
}

// ---------------- weight fp32 -> bf16 conversion ----------------
__global__ void convert_weights(const float* __restrict__ ewhh0, const float* __restrict__ ewih,
                                const float* __restrict__ ewhh, const float* __restrict__ dwhh0,
                                const float* __restrict__ dwih, const float* __restrict__ dwhh,
                                const float* __restrict__ lin1w, unsigned short* __restrict__ wb) {
  int i = blockIdx.x * 256 + threadIdx.x;
  if (i >= W_TOTAL) return;
  float v;
  if (i < O_EWIH)       v = ewhh0[i];
  else if (i < O_EWHH)  v = ewih[i - O_EWIH];
  else if (i < O_DWHH0) v = ewhh[i - O_EWHH];
  else if (i < O_DWIH)  v = dwhh0[i - O_DWHH0];
  else if (i < O_DWHH)  v = dwih[i - O_DWIH];
  else if (i < O_LIN1)  v = dwhh[i - O_DWHH];
  else                  v = lin1w[i - O_LIN1];
  wb[i] = f2bf(v);
}

__global__ void zero_loss_k(float* out) { out[LOSS_OFF] = 0.f; }

// ---------------- main persistent kernel ----------------
// grid = 128 blocks (M=32 batch rows each), block = 512 threads (8 waves).
// Wave w owns hidden units j in [16w, 16w+16): gate tiles at n = j, j+128, j+256,
// so r/z/n for a unit land in the same lane (C-layout col=lane&15=j, row=quad*4+reg=m).
// h state: fp32 master in registers (lane-owned (j, 8 m's)), bf16 copy in LDS for
// MFMA A-frags, double-buffered by step parity -> 1 barrier per layer-step.
// LDS bf16 h rows are XOR-chunk-swizzled (chunk' = chunk ^ (m&15)) to kill the
// 16-way ds_read_b128 bank conflict of the naive [m][k] layout.
__global__ __launch_bounds__(512, 2) void gru_seq2seq(
    const float* __restrict__ inp, const float* __restrict__ tgt,
    const float* __restrict__ enc_wih0, const float* __restrict__ enc_bih,
    const float* __restrict__ enc_bhh, const float* __restrict__ dec_wih0,
    const float* __restrict__ dec_bih, const float* __restrict__ dec_bhh,
    const float* __restrict__ lin1_b, const float* __restrict__ lin2_w,
    const float* __restrict__ lin2_b, const unsigned short* __restrict__ wb,
    float* __restrict__ out) {
  const int tid = threadIdx.x;
  const int wave = tid >> 6;
  const int lane = tid & 63;
  const int ln = lane & 15;
  const int quad = lane >> 4;
  const int b0 = blockIdx.x * 32;
  const int jb = wave << 4;
  const int j = jb + ln;  // this lane's hidden unit (epilogue + B-frag row base)

  __shared__ unsigned short hb[2][4][32][128];  // [parity][layer][m][swizzled k]
  __shared__ float xbuf[2][32][4];
  __shared__ float biasi[4][384];
  __shared__ float biash[4][384];
  __shared__ float wih0s[384][4];
  __shared__ float lin1bs[128];
  __shared__ float lin2ws[4][129];
  __shared__ float lin2bs[4];
  __shared__ float relu_s[32][129];
  __shared__ float red[8];

  for (int i = tid; i < 2 * 4 * 32 * 128; i += 512) ((unsigned short*)hb)[i] = 0;
  if (tid < 128) lin1bs[tid] = lin1_b[tid];
  { int e = tid >> 7, k = tid & 127; lin2ws[e][k] = lin2_w[e * 128 + k]; }
  if (tid < 4) lin2bs[tid] = lin2_b[tid];

  float hreg[4][8];  // [layer][mt*4+r] fp32 master of h for this lane's (j, m) set
#pragma unroll
  for (int l = 0; l < 4; l++)
#pragma unroll
    for (int i = 0; i < 8; i++) hreg[l][i] = 0.f;
  float loss_local = 0.f;

  // decoder_output[:, 0, :] = inp[:, 0, :]
  if (tid < 128) {
    int m = tid >> 2, e = tid & 3;
    out[DEC_OUT_OFF + (b0 + m) * 400 + e] = inp[(b0 + m) * 256 + e];
  }

  for (int ph = 0; ph < 2; ph++) {
    const float* bih = ph ? dec_bih : enc_bih;
    const float* bhh = ph ? dec_bhh : enc_bhh;
    const float* wih0 = ph ? dec_wih0 : enc_wih0;
    for (int i = tid; i < 1536; i += 512) {
      ((float*)biasi)[i] = bih[i];
      ((float*)biash)[i] = bhh[i];
      ((float*)wih0s)[i] = wih0[i];
    }
    // step-0 input: both phases start from inp[:, 0, :]
    if (tid < 128) {
      int m = tid >> 2, e = tid & 3;
      xbuf[0][m][e] = inp[(b0 + m) * 256 + e];
    }
    __syncthreads();

    const int T = ph ? T_DEC : T_ENC;
    const unsigned short* Whh0 = wb + (ph ? O_DWHH0 : O_EWHH0);
    const unsigned short* WihB = wb + (ph ? O_DWIH : O_EWIH);
    const unsigned short* WhhB = wb + (ph ? O_DWHH : O_EWHH);

    for (int t = 0; t < T; t++) {
      const int p = t & 1;
      for (int l = 0; l < 4; l++) {
        f32x4 acc_r[2], acc_z[2], acc_ngi[2], acc_ngh[2];
#pragma unroll
        for (int mt = 0; mt < 2; mt++) {
          acc_r[mt] = {0.f, 0.f, 0.f, 0.f};
          acc_z[mt] = {0.f, 0.f, 0.f, 0.f};
          acc_ngi[mt] = {0.f, 0.f, 0.f, 0.f};
          acc_ngh[mt] = {0.f, 0.f, 0.f, 0.f};
        }
        const unsigned short* Wh = l ? (WhhB + (l - 1) * 49152) : Whh0;
        const unsigned short* Wi = l ? (WihB + (l - 1) * 49152) : WihB;
#pragma unroll
        for (int ks = 0; ks < 4; ks++) {
          const int wofs = ks * 32 + quad * 8;
          short8_t b_rh = *(const short8_t*)(Wh + j * 128 + wofs);
          short8_t b_zh = *(const short8_t*)(Wh + (128 + j) * 128 + wofs);
          short8_t b_nh = *(const short8_t*)(Wh + (256 + j) * 128 + wofs);
          const int pc = (((ks * 4 + quad) ^ ln) << 3);
          if (l) {
            short8_t b_ri = *(const short8_t*)(Wi + j * 128 + wofs);
            short8_t b_zi = *(const short8_t*)(Wi + (128 + j) * 128 + wofs);
            short8_t b_ni = *(const short8_t*)(Wi + (256 + j) * 128 + wofs);
#pragma unroll
            for (int mt = 0; mt < 2; mt++) {
              const int m = mt * 16 + ln;
              short8_t a_h = *(const short8_t*)&hb[1 - p][l][m][pc];
              short8_t a_x = *(const short8_t*)&hb[p][l - 1][m][pc];
              acc_r[mt] = MFMA16(a_h, b_rh, acc_r[mt]);
              acc_r[mt] = MFMA16(a_x, b_ri, acc_r[mt]);
              acc_z[mt] = MFMA16(a_h, b_zh, acc_z[mt]);
              acc_z[mt] = MFMA16(a_x, b_zi, acc_z[mt]);
              acc_ngh[mt] = MFMA16(a_h, b_nh, acc_ngh[mt]);
              acc_ngi[mt] = MFMA16(a_x, b_ni, acc_ngi[mt]);
            }
          } else {
#pragma unroll
            for (int mt = 0; mt < 2; mt++) {
              const int m = mt * 16 + ln;
              short8_t a_h = *(const short8_t*)&hb[1 - p][l][m][pc];
              acc_r[mt] = MFMA16(a_h, b_rh, acc_r[mt]);
              acc_z[mt] = MFMA16(a_h, b_zh, acc_z[mt]);
              acc_ngh[mt] = MFMA16(a_h, b_nh, acc_ngh[mt]);
            }
          }
        }
        // ---- epilogue (in-register gate triplets) ----
        const float bir = biasi[l][j], biz = biasi[l][128 + j], bin = biasi[l][256 + j];
        const float bhr = biash[l][j], bhz = biash[l][128 + j], bhn = biash[l][256 + j];
        f32x4 wr, wz, wn;
        if (l == 0) {
          wr = *(const f32x4*)&wih0s[j][0];
          wz = *(const f32x4*)&wih0s[128 + j][0];
          wn = *(const f32x4*)&wih0s[256 + j][0];
        }
#pragma unroll
        for (int mt = 0; mt < 2; mt++) {
#pragma unroll
          for (int r = 0; r < 4; r++) {
            const int m = mt * 16 + quad * 4 + r;
            float gir, giz, gin;
            if (l == 0) {  // E=4 input GEMM done as 4 VALU MACs
              f32x4 xv = *(const f32x4*)&xbuf[p][m][0];
              gir = xv[0] * wr[0] + xv[1] * wr[1] + xv[2] * wr[2] + xv[3] * wr[3];
              giz = xv[0] * wz[0] + xv[1] * wz[1] + xv[2] * wz[2] + xv[3] * wz[3];
              gin = xv[0] * wn[0] + xv[1] * wn[1] + xv[2] * wn[2] + xv[3] * wn[3];
            } else {
              gir = 0.f; giz = 0.f; gin = acc_ngi[mt][r];
            }
            const float rg = sigm(acc_r[mt][r] + gir + bir + bhr);
            const float zg = sigm(acc_z[mt][r] + giz + biz + bhz);
            const float ng = tanh_fast(gin + bin + rg * (acc_ngh[mt][r] + bhn));
            const float hn = (1.f - zg) * ng + zg * hreg[l][mt * 4 + r];
            hreg[l][mt * 4 + r] = hn;
            const int pcw = ((((j >> 3) ^ (m & 15)) << 3) | (j & 7));
            hb[p][l][m][pcw] = f2bf(hn);
            if (!ph) {
              if (l == 3) out[ENC_OUT_OFF + ((b0 + m) * 64 + t) * 128 + j] = hn;
              if (t == T_ENC - 1) out[ENC_HID_OFF + (l * 4096 + b0 + m) * 128 + j] = hn;
            } else if (t == T_DEC - 1) {
              out[DEC_HID_OFF + (l * 4096 + b0 + m) * 128 + j] = hn;
            }
          }
        }
        // prefetch next step's input before the barrier (readers come after it)
        if (l == 3 && (t + 1) < T && tid < 128) {
          int m = tid >> 2, e = tid & 3;
          float xv = ph ? tgt[(b0 + m) * 400 + (t + 1) * 4 + e]
                        : inp[(b0 + m) * 256 + (t + 1) * 4 + e];
          xbuf[1 - p][m][e] = xv;
        }
        __syncthreads();
      }  // layer

      if (ph) {
        // ---- lin1 (128x128) via MFMA: wave w owns output cols j ----
        f32x4 a1[2];
        a1[0] = {0.f, 0.f, 0.f, 0.f};
        a1[1] = {0.f, 0.f, 0.f, 0.f};
        const unsigned short* W1 = wb + O_LIN1;
#pragma unroll
        for (int ks = 0; ks < 4; ks++) {
          short8_t bw = *(const short8_t*)(W1 + j * 128 + ks * 32 + quad * 8);
          const int pc = (((ks * 4 + quad) ^ ln) << 3);
#pragma unroll
          for (int mt = 0; mt < 2; mt++) {
            short8_t ah = *(const short8_t*)&hb[p][3][mt * 16 + ln][pc];
            a1[mt] = MFMA16(ah, bw, a1[mt]);
          }
        }
        const float l1b = lin1bs[j];
#pragma unroll
        for (int mt = 0; mt < 2; mt++)
#pragma unroll
          for (int r = 0; r < 4; r++) {
            const int m = mt * 16 + quad * 4 + r;
            const float v = a1[mt][r] + l1b;
            relu_s[m][j] = v > 0.f ? v : 0.f;
          }
        __syncthreads();
        // ---- lin2 (4x128) + loss, threads 0..127 ----
        if (tid < 128) {
          const int m = tid >> 2, e = tid & 3;
          float acc = lin2bs[e];
#pragma unroll 8
          for (int k = 0; k < 128; k++) acc += relu_s[m][k] * lin2ws[e][k];
          const int oidx = (b0 + m) * 400 + (t + 1) * 4 + e;
          out[DEC_OUT_OFF + oidx] = acc;
          const float d = acc - tgt[oidx];
          loss_local += d * d;
        }
      }
    }  // t
  }  // phase

  // ---- loss reduction: wave shuffle -> LDS -> one atomicAdd per block ----
  loss_local *= (1.f / 16384.f);  // mean over (B=4096, E=4)
#pragma unroll
  for (int off = 32; off; off >>= 1) loss_local += __shfl_down(loss_local, off);
  if (lane == 0) red[wave] = loss_local;
  __syncthreads();
  if (tid == 0) {
    float s = 0.f;
#pragma unroll
    for (int w = 0; w < 8; w++) s += red[w];
    atomicAdd(&out[LOSS_OFF], s);
  }
}

// ---------------- launch ----------------
extern "C" void kernel_launch(void* const* d_in, const int* in_sizes, int n_in,
                              void* d_out, int out_size, void* d_ws, size_t ws_size,
                              hipStream_t stream) {
  const float* inp      = (const float*)d_in[0];
  const float* tgt      = (const float*)d_in[1];
  const float* enc_wih0 = (const float*)d_in[2];
  const float* enc_whh0 = (const float*)d_in[3];
  const float* enc_wih  = (const float*)d_in[4];
  const float* enc_whh  = (const float*)d_in[5];
  const float* enc_bih  = (const float*)d_in[6];
  const float* enc_bhh  = (const float*)d_in[7];
  const float* dec_wih0 = (const float*)d_in[8];
  const float* dec_whh0 = (const float*)d_in[9];
  const float* dec_wih  = (const float*)d_in[10];
  const float* dec_whh  = (const float*)d_in[11];
  const float* dec_bih  = (const float*)d_in[12];
  const float* dec_bhh  = (const float*)d_in[13];
  const float* lin1_w   = (const float*)d_in[14];
  const float* lin1_b   = (const float*)d_in[15];
  const float* lin2_w   = (const float*)d_in[16];
  const float* lin2_b   = (const float*)d_in[17];
  unsigned short* wb = (unsigned short*)d_ws;
  float* out = (float*)d_out;

  hipLaunchKernelGGL(convert_weights, dim3((W_TOTAL + 255) / 256), dim3(256), 0, stream,
                     enc_whh0, enc_wih, enc_whh, dec_whh0, dec_wih, dec_whh, lin1_w, wb);
  hipLaunchKernelGGL(zero_loss_k, dim3(1), dim3(1), 0, stream, out);
  hipLaunchKernelGGL(gru_seq2seq, dim3(128), dim3(512), 0, stream,
                     inp, tgt, enc_wih0, enc_bih, enc_bhh, dec_wih0, dec_bih, dec_bhh,
                     lin1_b, lin2_w, lin2_b, wb, out);
}

// Round 2
// 4366.114 us; speedup vs baseline: 1.0078x; 1.0078x over previous
//
#include <hip/hip_runtime.h>

// ---------------- constants ----------------
#define T_ENC 64
#define T_DEC 99

// bf16 weight workspace layout (elements), fragment-permuted:
// per-phase blob = [L0: 3 slots][L1: 6 slots][L2: 6 slots][L3: 6 slots]
// slot = one (gate,matrix) B-operand for all 8 waves:
//   slot[w][ks][lane][e]  (8*4*64*8 = 16384 els) with lane=(quad<<4)|ln,
//   element = W[g*128 + w*16 + ln][ks*32 + quad*8 + e]
// so a wave's load of (slot,ks) is 64 lanes * 16B contiguous = 1 KiB coalesced.
#define SLOT    16384
#define PH_BLOB 344064          // 21 slots
#define O_LIN1  688128          // 1 slot (lin1 B-frags)
#define W_TOTAL 704512

// output layout (f32 elements)
#define DEC_OUT_OFF 0
#define DEC_HID_OFF 1638400
#define ENC_OUT_OFF 3735552
#define ENC_HID_OFF 37289984
#define LOSS_OFF    39387136

typedef short short8_t __attribute__((ext_vector_type(8)));
typedef float f32x4 __attribute__((ext_vector_type(4)));

#define MFMA16(a, b, c) __builtin_amdgcn_mfma_f32_16x16x32_bf16((a), (b), (c), 0, 0, 0)

__device__ __forceinline__ unsigned short f2bf(float f) {
  unsigned u = __builtin_bit_cast(unsigned, f);
  u = (u + 0x7FFFu + ((u >> 16) & 1u)) >> 16;
  return (unsigned short)u;
}
// fast sigmoid/tanh: v_exp_f32 + v_rcp_f32, no fp32 div sequence
__device__ __forceinline__ float sigm(float x) {
  return __builtin_amdgcn_rcpf(1.f + __expf(-x));
}
__device__ __forceinline__ float tanh_fast(float x) {
  x = fminf(fmaxf(x, -15.f), 15.f);
  float e = __expf(-2.f * x);               // e in [~0, 1e13] bounded
  return (1.f - e) * __builtin_amdgcn_rcpf(1.f + e);
}

// ---------------- weight fp32 -> bf16 fragment-permute ----------------
__global__ void convert_weights(const float* __restrict__ ewhh0, const float* __restrict__ ewih,
                                const float* __restrict__ ewhh, const float* __restrict__ dwhh0,
                                const float* __restrict__ dwih, const float* __restrict__ dwhh,
                                const float* __restrict__ lin1w, unsigned short* __restrict__ wb) {
  int i = blockIdx.x * 256 + threadIdx.x;
  if (i >= W_TOTAL) return;
  float v;
  if (i < O_LIN1) {
    const int ph = i / PH_BLOB;
    const int li = i % PH_BLOB;
    const float* whh0 = ph ? dwhh0 : ewhh0;
    const float* wih  = ph ? dwih  : ewih;
    const float* whh  = ph ? dwhh  : ewhh;
    int l, s, r;
    if (li < 3 * SLOT) { l = 0; s = li / SLOT; r = li % SLOT; }
    else {
      int q = li - 3 * SLOT;
      l = 1 + q / (6 * SLOT);
      int lq = q % (6 * SLOT);
      s = lq / SLOT; r = lq % SLOT;
    }
    const int w = r >> 11, ks = (r >> 9) & 3, lane = (r >> 3) & 63, e = r & 7;
    const int quad = lane >> 4, ln = lane & 15;
    const int g = (s < 3) ? s : (s - 3);
    const int row = g * 128 + w * 16 + ln;
    const int col = ks * 32 + quad * 8 + e;
    if (l == 0)      v = whh0[row * 128 + col];
    else if (s < 3)  v = whh[(l - 1) * 49152 + row * 128 + col];
    else             v = wih[(l - 1) * 49152 + row * 128 + col];
  } else {
    const int r = i - O_LIN1;
    const int w = r >> 11, ks = (r >> 9) & 3, lane = (r >> 3) & 63, e = r & 7;
    const int quad = lane >> 4, ln = lane & 15;
    v = lin1w[(w * 16 + ln) * 128 + ks * 32 + quad * 8 + e];
  }
  wb[i] = f2bf(v);
}

__global__ void zero_loss_k(float* out) { out[LOSS_OFF] = 0.f; }

// ---------------- main persistent kernel ----------------
// grid = 128 blocks (M=32 batch rows each), block = 512 threads (8 waves).
// Wave w owns hidden units j in [16w, 16w+16): gate tiles at n = j, j+128, j+256,
// so r/z/n for a unit land in the same lane (C-layout col=lane&15=j, row=quad*4+reg=m).
// Weights are pre-permuted to fragment order -> every B-frag load is a single
// coalesced 1 KiB wave transaction at SGPR-base + imm offset (R1 fix: the naive
// row-strided loads were 64-lines-per-instr uncoalesced => 16 kcy/layer-step).
// h state: fp32 master in registers, bf16 copy in LDS (XOR-chunk swizzled),
// double-buffered by step parity -> 1 barrier per layer-step.
__global__ __launch_bounds__(512, 2) void gru_seq2seq(
    const float* __restrict__ inp, const float* __restrict__ tgt,
    const float* __restrict__ enc_wih0, const float* __restrict__ enc_bih,
    const float* __restrict__ enc_bhh, const float* __restrict__ dec_wih0,
    const float* __restrict__ dec_bih, const float* __restrict__ dec_bhh,
    const float* __restrict__ lin1_b, const float* __restrict__ lin2_w,
    const float* __restrict__ lin2_b, const unsigned short* __restrict__ wb,
    float* __restrict__ out) {
  const int tid = threadIdx.x;
  const int wave = tid >> 6;
  const int lane = tid & 63;
  const int ln = lane & 15;
  const int quad = lane >> 4;
  const int b0 = blockIdx.x * 32;
  const int j = (wave << 4) + ln;  // this lane's hidden unit (epilogue)

  __shared__ unsigned short hb[2][4][32][128];  // [parity][layer][m][swizzled k]
  __shared__ float xbuf[2][32][4];
  __shared__ float biasi[4][384];
  __shared__ float biash[4][384];
  __shared__ float wih0s[384][4];
  __shared__ float lin1bs[128];
  __shared__ float lin2ws[4][129];
  __shared__ float lin2bs[4];
  __shared__ float relu_s[32][129];
  __shared__ float red[8];

  for (int i = tid; i < 2 * 4 * 32 * 128; i += 512) ((unsigned short*)hb)[i] = 0;
  if (tid < 128) lin1bs[tid] = lin1_b[tid];
  { int e = tid >> 7, k = tid & 127; lin2ws[e][k] = lin2_w[e * 128 + k]; }
  if (tid < 4) lin2bs[tid] = lin2_b[tid];

  float hreg[4][8];  // [layer][mt*4+r] fp32 master of h for this lane's (j, m) set
#pragma unroll
  for (int l = 0; l < 4; l++)
#pragma unroll
    for (int i = 0; i < 8; i++) hreg[l][i] = 0.f;
  float loss_local = 0.f;

  // decoder_output[:, 0, :] = inp[:, 0, :]
  if (tid < 128) {
    int m = tid >> 2, e = tid & 3;
    out[DEC_OUT_OFF + (b0 + m) * 400 + e] = inp[(b0 + m) * 256 + e];
  }

  // per-wave fragment base offset inside a slot: [w][ks][lane][8]
  const int fofs = wave * 2048 + lane * 8;

  for (int ph = 0; ph < 2; ph++) {
    const float* bih = ph ? dec_bih : enc_bih;
    const float* bhh = ph ? dec_bhh : enc_bhh;
    const float* wih0 = ph ? dec_wih0 : enc_wih0;
    for (int i = tid; i < 1536; i += 512) {
      ((float*)biasi)[i] = bih[i];
      ((float*)biash)[i] = bhh[i];
      ((float*)wih0s)[i] = wih0[i];
    }
    // step-0 input: both phases start from inp[:, 0, :]
    if (tid < 128) {
      int m = tid >> 2, e = tid & 3;
      xbuf[0][m][e] = inp[(b0 + m) * 256 + e];
    }
    __syncthreads();

    const int T = ph ? T_DEC : T_ENC;
    const unsigned short* PB = wb + (ph ? PH_BLOB : 0);

    for (int t = 0; t < T; t++) {
      const int p = t & 1;
      for (int l = 0; l < 4; l++) {
        f32x4 acc_r[2], acc_z[2], acc_ngi[2], acc_ngh[2];
#pragma unroll
        for (int mt = 0; mt < 2; mt++) {
          acc_r[mt] = {0.f, 0.f, 0.f, 0.f};
          acc_z[mt] = {0.f, 0.f, 0.f, 0.f};
          acc_ngi[mt] = {0.f, 0.f, 0.f, 0.f};
          acc_ngh[mt] = {0.f, 0.f, 0.f, 0.f};
        }
        const unsigned short* LB =
            PB + (l == 0 ? 0 : (3 * SLOT + (l - 1) * 6 * SLOT)) + fofs;
#pragma unroll
        for (int ks = 0; ks < 4; ks++) {
          const int ko = ks * 512;
          short8_t b_rh = *(const short8_t*)(LB + 0 * SLOT + ko);
          short8_t b_zh = *(const short8_t*)(LB + 1 * SLOT + ko);
          short8_t b_nh = *(const short8_t*)(LB + 2 * SLOT + ko);
          const int pc = (((ks * 4 + quad) ^ ln) << 3);
          if (l) {
            short8_t b_ri = *(const short8_t*)(LB + 3 * SLOT + ko);
            short8_t b_zi = *(const short8_t*)(LB + 4 * SLOT + ko);
            short8_t b_ni = *(const short8_t*)(LB + 5 * SLOT + ko);
#pragma unroll
            for (int mt = 0; mt < 2; mt++) {
              const int m = mt * 16 + ln;
              short8_t a_h = *(const short8_t*)&hb[1 - p][l][m][pc];
              short8_t a_x = *(const short8_t*)&hb[p][l - 1][m][pc];
              acc_r[mt] = MFMA16(a_h, b_rh, acc_r[mt]);
              acc_r[mt] = MFMA16(a_x, b_ri, acc_r[mt]);
              acc_z[mt] = MFMA16(a_h, b_zh, acc_z[mt]);
              acc_z[mt] = MFMA16(a_x, b_zi, acc_z[mt]);
              acc_ngh[mt] = MFMA16(a_h, b_nh, acc_ngh[mt]);
              acc_ngi[mt] = MFMA16(a_x, b_ni, acc_ngi[mt]);
            }
          } else {
#pragma unroll
            for (int mt = 0; mt < 2; mt++) {
              const int m = mt * 16 + ln;
              short8_t a_h = *(const short8_t*)&hb[1 - p][l][m][pc];
              acc_r[mt] = MFMA16(a_h, b_rh, acc_r[mt]);
              acc_z[mt] = MFMA16(a_h, b_zh, acc_z[mt]);
              acc_ngh[mt] = MFMA16(a_h, b_nh, acc_ngh[mt]);
            }
          }
        }
        // ---- epilogue (in-register gate triplets) ----
        const float br = biasi[l][j] + biash[l][j];
        const float bz = biasi[l][128 + j] + biash[l][128 + j];
        const float bin = biasi[l][256 + j], bhn = biash[l][256 + j];
        f32x4 wr, wz, wn;
        if (l == 0) {
          wr = *(const f32x4*)&wih0s[j][0];
          wz = *(const f32x4*)&wih0s[128 + j][0];
          wn = *(const f32x4*)&wih0s[256 + j][0];
        }
#pragma unroll
        for (int mt = 0; mt < 2; mt++) {
#pragma unroll
          for (int r = 0; r < 4; r++) {
            const int m = mt * 16 + quad * 4 + r;
            float gir, giz, gin;
            if (l == 0) {  // E=4 input GEMM done as 4 VALU MACs
              f32x4 xv = *(const f32x4*)&xbuf[p][m][0];
              gir = xv[0] * wr[0] + xv[1] * wr[1] + xv[2] * wr[2] + xv[3] * wr[3];
              giz = xv[0] * wz[0] + xv[1] * wz[1] + xv[2] * wz[2] + xv[3] * wz[3];
              gin = xv[0] * wn[0] + xv[1] * wn[1] + xv[2] * wn[2] + xv[3] * wn[3];
            } else {
              gir = 0.f; giz = 0.f; gin = acc_ngi[mt][r];
            }
            const float rg = sigm(acc_r[mt][r] + gir + br);
            const float zg = sigm(acc_z[mt][r] + giz + bz);
            const float ng = tanh_fast(gin + bin + rg * (acc_ngh[mt][r] + bhn));
            const float hn = (1.f - zg) * ng + zg * hreg[l][mt * 4 + r];
            hreg[l][mt * 4 + r] = hn;
            const int pcw = ((((j >> 3) ^ (m & 15)) << 3) | (j & 7));
            hb[p][l][m][pcw] = f2bf(hn);
            if (!ph) {
              if (l == 3) out[ENC_OUT_OFF + ((b0 + m) * 64 + t) * 128 + j] = hn;
              if (t == T_ENC - 1) out[ENC_HID_OFF + (l * 4096 + b0 + m) * 128 + j] = hn;
            } else if (t == T_DEC - 1) {
              out[DEC_HID_OFF + (l * 4096 + b0 + m) * 128 + j] = hn;
            }
          }
        }
        // prefetch next step's input before the barrier (readers come after it)
        if (l == 3 && (t + 1) < T && tid < 128) {
          int m = tid >> 2, e = tid & 3;
          float xv = ph ? tgt[(b0 + m) * 400 + (t + 1) * 4 + e]
                        : inp[(b0 + m) * 256 + (t + 1) * 4 + e];
          xbuf[1 - p][m][e] = xv;
        }
        __syncthreads();
      }  // layer

      if (ph) {
        // ---- lin1 (128x128) via MFMA: wave w owns output cols j ----
        f32x4 a1[2];
        a1[0] = {0.f, 0.f, 0.f, 0.f};
        a1[1] = {0.f, 0.f, 0.f, 0.f};
        const unsigned short* W1 = wb + O_LIN1 + fofs;
#pragma unroll
        for (int ks = 0; ks < 4; ks++) {
          short8_t bw = *(const short8_t*)(W1 + ks * 512);
          const int pc = (((ks * 4 + quad) ^ ln) << 3);
#pragma unroll
          for (int mt = 0; mt < 2; mt++) {
            short8_t ah = *(const short8_t*)&hb[p][3][mt * 16 + ln][pc];
            a1[mt] = MFMA16(ah, bw, a1[mt]);
          }
        }
        const float l1b = lin1bs[j];
#pragma unroll
        for (int mt = 0; mt < 2; mt++)
#pragma unroll
          for (int r = 0; r < 4; r++) {
            const int m = mt * 16 + quad * 4 + r;
            const float v = a1[mt][r] + l1b;
            relu_s[m][j] = v > 0.f ? v : 0.f;
          }
        __syncthreads();
        // ---- lin2 (4x128) + loss, threads 0..127 ----
        if (tid < 128) {
          const int m = tid >> 2, e = tid & 3;
          float acc = lin2bs[e];
#pragma unroll 8
          for (int k = 0; k < 128; k++) acc += relu_s[m][k] * lin2ws[e][k];
          const int oidx = (b0 + m) * 400 + (t + 1) * 4 + e;
          out[DEC_OUT_OFF + oidx] = acc;
          const float d = acc - tgt[oidx];
          loss_local += d * d;
        }
      }
    }  // t
  }  // phase

  // ---- loss reduction: wave shuffle -> LDS -> one atomicAdd per block ----
  loss_local *= (1.f / 16384.f);  // mean over (B=4096, E=4)
#pragma unroll
  for (int off = 32; off; off >>= 1) loss_local += __shfl_down(loss_local, off);
  if (lane == 0) red[wave] = loss_local;
  __syncthreads();
  if (tid == 0) {
    float s = 0.f;
#pragma unroll
    for (int w = 0; w < 8; w++) s += red[w];
    atomicAdd(&out[LOSS_OFF], s);
  }
}

// ---------------- launch ----------------
extern "C" void kernel_launch(void* const* d_in, const int* in_sizes, int n_in,
                              void* d_out, int out_size, void* d_ws, size_t ws_size,
                              hipStream_t stream) {
  const float* inp      = (const float*)d_in[0];
  const float* tgt      = (const float*)d_in[1];
  const float* enc_wih0 = (const float*)d_in[2];
  const float* enc_whh0 = (const float*)d_in[3];
  const float* enc_wih  = (const float*)d_in[4];
  const float* enc_whh  = (const float*)d_in[5];
  const float* enc_bih  = (const float*)d_in[6];
  const float* enc_bhh  = (const float*)d_in[7];
  const float* dec_wih0 = (const float*)d_in[8];
  const float* dec_whh0 = (const float*)d_in[9];
  const float* dec_wih  = (const float*)d_in[10];
  const float* dec_whh  = (const float*)d_in[11];
  const float* dec_bih  = (const float*)d_in[12];
  const float* dec_bhh  = (const float*)d_in[13];
  const float* lin1_w   = (const float*)d_in[14];
  const float* lin1_b   = (const float*)d_in[15];
  const float* lin2_w   = (const float*)d_in[16];
  const float* lin2_b   = (const float*)d_in[17];
  unsigned short* wb = (unsigned short*)d_ws;
  float* out = (float*)d_out;

  hipLaunchKernelGGL(convert_weights, dim3((W_TOTAL + 255) / 256), dim3(256), 0, stream,
                     enc_whh0, enc_wih, enc_whh, dec_whh0, dec_wih, dec_whh, lin1_w, wb);
  hipLaunchKernelGGL(zero_loss_k, dim3(1), dim3(1), 0, stream, out);
  hipLaunchKernelGGL(gru_seq2seq, dim3(128), dim3(512), 0, stream,
                     inp, tgt, enc_wih0, enc_bih, enc_bhh, dec_wih0, dec_bih, dec_bhh,
                     lin1_b, lin2_w, lin2_b, wb, out);
}

// Round 3
// 1690.893 us; speedup vs baseline: 2.6023x; 2.5821x over previous
//
#include <hip/hip_runtime.h>

// ---------------- constants ----------------
#define T_ENC 64
#define T_DEC 99

// bf16 weight workspace (elements), fragment-permuted, uniform 6 slots/layer:
// phase blob = 4 layers x 6 slots; slot s: 0..2 = h-side gates r/z/n, 3..5 = x-side
// gates r/z/n (layer 0 x-side = wih0 zero-padded to K=128).
// slot[w][ks][lane][e] (8*4*64*8=16384 els): element = W[g*128 + w*16 + ln][ks*32 + quad*8 + e]
// -> a wave's (slot,ks) load is 64 lanes x 16B contiguous = 1 KiB coalesced.
#define SLOT    16384
#define PH_BLOB 393216          // 24 slots
#define O_LIN1  786432          // 1 slot (lin1 B-frags)
#define W_TOTAL 802816

// output layout (f32 elements)
#define DEC_OUT_OFF 0
#define DEC_HID_OFF 1638400
#define ENC_OUT_OFF 3735552
#define ENC_HID_OFF 37289984
#define LOSS_OFF    39387136

typedef short short8_t __attribute__((ext_vector_type(8)));
typedef float f32x4 __attribute__((ext_vector_type(4)));

#define MFMA16(a, b, c) __builtin_amdgcn_mfma_f32_16x16x32_bf16((a), (b), (c), 0, 0, 0)

__device__ __forceinline__ unsigned short f2bf(float f) {
  unsigned u = __builtin_bit_cast(unsigned, f);
  u = (u + 0x7FFFu + ((u >> 16) & 1u)) >> 16;
  return (unsigned short)u;
}
__device__ __forceinline__ float sigm(float x) {
  return __builtin_amdgcn_rcpf(1.f + __expf(-x));
}
__device__ __forceinline__ float tanh_fast(float x) {
  x = fminf(fmaxf(x, -15.f), 15.f);
  float e = __expf(-2.f * x);
  return (1.f - e) * __builtin_amdgcn_rcpf(1.f + e);
}

// ---------------- weight fp32 -> bf16 fragment-permute ----------------
__global__ void convert_weights(const float* __restrict__ ewih0, const float* __restrict__ ewhh0,
                                const float* __restrict__ ewih, const float* __restrict__ ewhh,
                                const float* __restrict__ dwih0, const float* __restrict__ dwhh0,
                                const float* __restrict__ dwih, const float* __restrict__ dwhh,
                                const float* __restrict__ lin1w, unsigned short* __restrict__ wb) {
  int i = blockIdx.x * 256 + threadIdx.x;
  if (i >= W_TOTAL) return;
  float v;
  if (i < O_LIN1) {
    const int ph = i / PH_BLOB;
    const int li = i % PH_BLOB;
    const float* wih0 = ph ? dwih0 : ewih0;
    const float* whh0 = ph ? dwhh0 : ewhh0;
    const float* wih  = ph ? dwih  : ewih;
    const float* whh  = ph ? dwhh  : ewhh;
    const int l = li / (6 * SLOT);
    const int r6 = li % (6 * SLOT);
    const int s = r6 / SLOT, r = r6 % SLOT;
    const int w = r >> 11, ks = (r >> 9) & 3, lane = (r >> 3) & 63, e = r & 7;
    const int quad = lane >> 4, ln = lane & 15;
    const int g = (s < 3) ? s : (s - 3);
    const int row = g * 128 + w * 16 + ln;
    const int col = ks * 32 + quad * 8 + e;
    if (s < 3) {  // h-side
      v = (l == 0) ? whh0[row * 128 + col] : whh[(l - 1) * 49152 + row * 128 + col];
    } else {      // x-side (layer 0: wih0 is [384][4], zero-padded beyond col 3)
      v = (l == 0) ? (col < 4 ? wih0[row * 4 + col] : 0.f)
                   : wih[(l - 1) * 49152 + row * 128 + col];
    }
  } else {
    const int r = i - O_LIN1;
    const int w = r >> 11, ks = (r >> 9) & 3, lane = (r >> 3) & 63, e = r & 7;
    const int quad = lane >> 4, ln = lane & 15;
    v = lin1w[(w * 16 + ln) * 128 + ks * 32 + quad * 8 + e];
  }
  wb[i] = f2bf(v);
}

__global__ void zero_loss_k(float* out) { out[LOSS_OFF] = 0.f; }

// ---------------- main persistent kernel ----------------
// grid = 256 blocks (M=16 batch rows each -> all 256 CUs), block = 512 threads (8 waves).
// Wave w owns hidden units j in [16w,16w+16); r/z/n for a unit land in the same lane
// (C-layout col=lane&15=j, row=quad*4+reg=m).
// KEY (R2 fix): t-loop and l-loop are unroll(1) so weight-fragment loads have
// loop-VARIANT addresses -> LICM cannot hoist them out of the t-loop (R2's 5.2 GB
// FETCH was hoisted-then-spilled frags reloaded from scratch every layer-step).
// 2-deep rotating register prefetch (buf[2][6]) hides L2 latency; fp32 h master
// lives in LDS (hf) because runtime-l indexing of a private array would go to scratch.
__global__ __launch_bounds__(512, 2) void gru_seq2seq(
    const float* __restrict__ inp, const float* __restrict__ tgt,
    const float* __restrict__ enc_bih, const float* __restrict__ enc_bhh,
    const float* __restrict__ dec_bih, const float* __restrict__ dec_bhh,
    const float* __restrict__ lin1_b, const float* __restrict__ lin2_w,
    const float* __restrict__ lin2_b, const unsigned short* __restrict__ wb,
    float* __restrict__ out) {
  const int tid = threadIdx.x;
  const int wave = tid >> 6;
  const int lane = tid & 63;
  const int ln = lane & 15;
  const int quad = lane >> 4;
  const int b0 = blockIdx.x * 16;
  const int j = (wave << 4) + ln;

  __shared__ unsigned short hb[2][4][16][128];  // bf16 h, [parity][layer][m][swz k]
  __shared__ unsigned short xt[2][16][128];     // bf16 x-tile, zero-padded K=128
  __shared__ float hf[4][16][128];              // fp32 h master
  __shared__ float biasi[4][384];
  __shared__ float biash[4][384];
  __shared__ float lin1bs[128];
  __shared__ float lin2ws[4][129];
  __shared__ float lin2bs[4];
  __shared__ float relu_s[16][129];

  for (int i = tid; i < 2 * 4 * 16 * 128; i += 512) ((unsigned short*)hb)[i] = 0;
  for (int i = tid; i < 2 * 16 * 128; i += 512) ((unsigned short*)xt)[i] = 0;
  for (int i = tid; i < 4 * 16 * 128; i += 512) ((float*)hf)[i] = 0.f;
  if (tid < 128) lin1bs[tid] = lin1_b[tid];
  { int e = tid >> 7, k = tid & 127; lin2ws[e][k] = lin2_w[e * 128 + k]; }
  if (tid < 4) lin2bs[tid] = lin2_b[tid];

  float loss_local = 0.f;

  // decoder_output[:, 0, :] = inp[:, 0, :]
  if (tid < 64) {
    int m = tid >> 2, e = tid & 3;
    out[DEC_OUT_OFF + (b0 + m) * 400 + e] = inp[(b0 + m) * 256 + e];
  }

  const int fofs = wave * 2048 + lane * 8;  // [w][ks][lane][8] within a slot

  // lin1 B-frags: register-resident for the whole kernel (16 VGPRs)
  short8_t w1f[4];
#pragma unroll
  for (int ks = 0; ks < 4; ks++)
    w1f[ks] = *(const short8_t*)(wb + O_LIN1 + fofs + ks * 512);

#pragma unroll 1
  for (int ph = 0; ph < 2; ph++) {
    const float* bih = ph ? dec_bih : enc_bih;
    const float* bhh = ph ? dec_bhh : enc_bhh;
    for (int i = tid; i < 1536; i += 512) {
      ((float*)biasi)[i] = bih[i];
      ((float*)biash)[i] = bhh[i];
    }
    // step-0 input for both phases: inp[:, 0, :]
    if (tid < 64) {
      int m = tid >> 2, e = tid & 3;
      xt[0][m][(m << 3) | e] = f2bf(inp[(b0 + m) * 256 + e]);
    }
    __syncthreads();

    const int T = ph ? T_DEC : T_ENC;
    const unsigned short* PB = wb + ph * PH_BLOB + fofs;

    // rotating prefetch: buf[ks&1] consumed, buf[(ks+1)&1] loading
    short8_t buf[2][6];
#pragma unroll
    for (int s = 0; s < 6; s++) buf[0][s] = *(const short8_t*)(PB + s * SLOT);

#pragma unroll 1
    for (int t = 0; t < T; t++) {
      const int p = t & 1;
#pragma unroll 1
      for (int l = 0; l < 4; l++) {
        const unsigned short* LB = PB + l * (6 * SLOT);
        const unsigned short* LBn = (l < 3) ? (LB + 6 * SLOT) : PB;  // next layer / next-t L0
        f32x4 ar = {0.f, 0.f, 0.f, 0.f}, az = {0.f, 0.f, 0.f, 0.f};
        f32x4 ani = {0.f, 0.f, 0.f, 0.f}, anh = {0.f, 0.f, 0.f, 0.f};
        const unsigned short* axb = l ? &hb[p][l - 1][0][0] : &xt[p][0][0];
        const unsigned short* ahb = &hb[1 - p][l][0][0];
#pragma unroll
        for (int ks = 0; ks < 4; ks++) {
          const unsigned short* src = (ks < 3) ? (LB + (ks + 1) * 512) : LBn;
#pragma unroll
          for (int s = 0; s < 6; s++)
            buf[(ks + 1) & 1][s] = *(const short8_t*)(src + s * SLOT);
          const int pc = (((ks * 4 + quad) ^ ln) << 3);
          short8_t a_h = *(const short8_t*)(ahb + ln * 128 + pc);
          short8_t a_x = *(const short8_t*)(axb + ln * 128 + pc);
          ar = MFMA16(a_h, buf[ks & 1][0], ar);
          ar = MFMA16(a_x, buf[ks & 1][3], ar);
          az = MFMA16(a_h, buf[ks & 1][1], az);
          az = MFMA16(a_x, buf[ks & 1][4], az);
          anh = MFMA16(a_h, buf[ks & 1][2], anh);
          ani = MFMA16(a_x, buf[ks & 1][5], ani);
        }
        // ---- epilogue ----
        const float br = biasi[l][j] + biash[l][j];
        const float bz = biasi[l][128 + j] + biash[l][128 + j];
        const float bin = biasi[l][256 + j], bhn = biash[l][256 + j];
#pragma unroll
        for (int r = 0; r < 4; r++) {
          const int m = quad * 4 + r;
          const float hp = hf[l][m][j];
          const float rg = sigm(ar[r] + br);
          const float zg = sigm(az[r] + bz);
          const float ng = tanh_fast(ani[r] + bin + rg * (anh[r] + bhn));
          const float hn = (1.f - zg) * ng + zg * hp;
          hf[l][m][j] = hn;
          hb[p][l][m][(((j >> 3) ^ m) << 3) | (j & 7)] = f2bf(hn);
          if (!ph) {
            if (l == 3) out[ENC_OUT_OFF + ((b0 + m) * 64 + t) * 128 + j] = hn;
            if (t == T_ENC - 1) out[ENC_HID_OFF + (l * 4096 + b0 + m) * 128 + j] = hn;
          } else if (t == T_DEC - 1) {
            out[DEC_HID_OFF + (l * 4096 + b0 + m) * 128 + j] = hn;
          }
        }
        // prefetch next step's x before the barrier (readers come after it)
        if (l == 3 && (t + 1) < T && tid < 64) {
          int m = tid >> 2, e = tid & 3;
          float xv = ph ? tgt[(b0 + m) * 400 + (t + 1) * 4 + e]
                        : inp[(b0 + m) * 256 + (t + 1) * 4 + e];
          xt[1 - p][m][(m << 3) | e] = f2bf(xv);
        }
        __syncthreads();
      }  // layer

      if (ph) {
        // ---- lin1 (128x128) via MFMA, register-resident weights ----
        f32x4 a1 = {0.f, 0.f, 0.f, 0.f};
        const unsigned short* h3 = &hb[p][3][0][0];
#pragma unroll
        for (int ks = 0; ks < 4; ks++) {
          const int pc = (((ks * 4 + quad) ^ ln) << 3);
          short8_t ah = *(const short8_t*)(h3 + ln * 128 + pc);
          a1 = MFMA16(ah, w1f[ks], a1);
        }
        const float l1b = lin1bs[j];
#pragma unroll
        for (int r = 0; r < 4; r++) {
          const int m = quad * 4 + r;
          const float v = a1[r] + l1b;
          relu_s[m][j] = v > 0.f ? v : 0.f;
        }
        __syncthreads();
        // ---- lin2 (4x128) + loss, threads 0..63 ----
        if (tid < 64) {
          const int m = tid >> 2, e = tid & 3;
          float acc = lin2bs[e];
#pragma unroll 8
          for (int k = 0; k < 128; k++) acc += relu_s[m][k] * lin2ws[e][k];
          const int oidx = (b0 + m) * 400 + (t + 1) * 4 + e;
          out[DEC_OUT_OFF + oidx] = acc;
          const float d = acc - tgt[oidx];
          loss_local += d * d;
        }
      }
    }  // t
  }  // phase

  // ---- loss reduction: only wave 0 has nonzero partials ----
  loss_local *= (1.f / 16384.f);  // mean over (B=4096, E=4)
#pragma unroll
  for (int off = 32; off; off >>= 1) loss_local += __shfl_down(loss_local, off);
  if (tid == 0) atomicAdd(&out[LOSS_OFF], loss_local);
}

// ---------------- launch ----------------
extern "C" void kernel_launch(void* const* d_in, const int* in_sizes, int n_in,
                              void* d_out, int out_size, void* d_ws, size_t ws_size,
                              hipStream_t stream) {
  const float* inp      = (const float*)d_in[0];
  const float* tgt      = (const float*)d_in[1];
  const float* enc_wih0 = (const float*)d_in[2];
  const float* enc_whh0 = (const float*)d_in[3];
  const float* enc_wih  = (const float*)d_in[4];
  const float* enc_whh  = (const float*)d_in[5];
  const float* enc_bih  = (const float*)d_in[6];
  const float* enc_bhh  = (const float*)d_in[7];
  const float* dec_wih0 = (const float*)d_in[8];
  const float* dec_whh0 = (const float*)d_in[9];
  const float* dec_wih  = (const float*)d_in[10];
  const float* dec_whh  = (const float*)d_in[11];
  const float* dec_bih  = (const float*)d_in[12];
  const float* dec_bhh  = (const float*)d_in[13];
  const float* lin1_w   = (const float*)d_in[14];
  const float* lin1_b   = (const float*)d_in[15];
  const float* lin2_w   = (const float*)d_in[16];
  const float* lin2_b   = (const float*)d_in[17];
  unsigned short* wb = (unsigned short*)d_ws;
  float* out = (float*)d_out;

  hipLaunchKernelGGL(convert_weights, dim3((W_TOTAL + 255) / 256), dim3(256), 0, stream,
                     enc_wih0, enc_whh0, enc_wih, enc_whh, dec_wih0, dec_whh0, dec_wih,
                     dec_whh, lin1_w, wb);
  hipLaunchKernelGGL(zero_loss_k, dim3(1), dim3(1), 0, stream, out);
  hipLaunchKernelGGL(gru_seq2seq, dim3(256), dim3(512), 0, stream,
                     inp, tgt, enc_bih, enc_bhh, dec_bih, dec_bhh,
                     lin1_b, lin2_w, lin2_b, wb, out);
}